// Round 8
// baseline (397.717 us; speedup 1.0000x reference)
//
#include <hip/hip_runtime.h>
#include <hip/hip_cooperative_groups.h>
#include <math.h>

namespace cg = cooperative_groups;

#define BATCH 32
#define SEQ   4096
#define DM    256
#define NS    64
#define TSTEP 16   // time steps per staged LDS tile

// z-space recurrence: z = a*z + u, x = B_tilde * z exactly.
// y = sum_n (C*B_tilde)[n] * z[n].
// chain = one (b,d) recurrence. 4 lanes per chain, 16 states per lane.
// wave = 64 lanes = 16 chains = (one b, 16 consecutive d).
// Fused single cooperative kernel: phase1 (local scans -> E_g), grid sync,
// per-wave combine of E_0..E_{g-1} (replaces pass2), phase3 (scan + y).
// Eliminates 2 launch gaps + the pass2 global round-trip (~70-85us of the
// r7 388us total). Fallback to the proven r7 3-kernel path if cooperative
// launch is unavailable.

// ---------------- fused cooperative kernel ----------------
__global__ __launch_bounds__(256, 2)
void fused_kernel(const float* __restrict__ u,
                  const float* __restrict__ log_dt,
                  const float* __restrict__ A_real,
                  const float* __restrict__ B,
                  const float* __restrict__ Cm,
                  float* __restrict__ S,
                  const float* __restrict__ x0,
                  float* __restrict__ y, int Tc, int C) {
    __shared__ float tiles[4][2][TSTEP][16];  // 8 KB: 4 waves x dbuf x tile
    int wid  = threadIdx.x >> 6;
    int lane = threadIdx.x & 63;
    int wave = (blockIdx.x * blockDim.x + threadIdx.x) >> 6;
    int w  = wave & 511;   // chain group within chunk
    int g  = wave >> 9;    // chunk
    int b  = w >> 4;
    int d0 = (w & 15) << 4;
    int c   = lane >> 2;   // chain within wave (0..15)
    int sub = lane & 3;    // quarter of the state vector
    int d   = d0 + c;
    int n0  = sub << 4;

    float dt = expf(log_dt[d]);  // DT_SCALE = 1.0
    const float* Ap = A_real + d * NS + n0;
    float a[16], z[16];
#pragma unroll
    for (int k = 0; k < 16; ++k)
        a[k] = expf(Ap[k] * dt);

    const size_t tadv = (size_t)TSTEP * DM;
    float* slot0 = &tiles[wid][0][0][0] + (lane << 2);  // lane's 16B in buf0
    const int ntiles = Tc / TSTEP;
    const size_t estride = (size_t)BATCH * DM * NS;

    // ---- phase 1: local z-scan from zero; publish end state E_g ----
    if (C > 1 && g < C - 1) {
#pragma unroll
        for (int k = 0; k < 16; ++k) z[k] = 0.0f;
        const float* gsrc = u + (size_t)b * SEQ * DM + (size_t)(g * Tc) * DM
                            + (size_t)(lane >> 2) * DM + d0 + ((lane & 3) << 2);
        float4 rnext = *(const float4*)gsrc;
        *(float4*)slot0 = rnext;
        gsrc += tadv;
        rnext = *(const float4*)gsrc;
        gsrc += tadv;
        for (int tile = 0; tile < ntiles; ++tile) {
            int cur = tile & 1;
            if (tile + 1 < ntiles)
                *(float4*)(slot0 + (((tile + 1) & 1) << 8)) = rnext;
            if (tile + 2 < ntiles) {
                rnext = *(const float4*)gsrc;
                gsrc += tadv;
            }
            const float* tb = &tiles[wid][cur][0][0] + c;
#pragma unroll
            for (int s = 0; s < TSTEP; ++s) {
                float uv = tb[s << 4];          // broadcast ds_read_b32
#pragma unroll
                for (int k = 0; k < 16; ++k)
                    z[k] = fmaf(a[k], z[k], uv);
            }
        }
        float* Sp = S + (((size_t)g * BATCH + b) * DM + d) * NS + n0;
        float4* Sp4 = (float4*)Sp;
#pragma unroll
        for (int j = 0; j < 4; ++j)
            Sp4[j] = make_float4(z[4*j], z[4*j+1], z[4*j+2], z[4*j+3]);
    }

    cg::this_grid().sync();

    // ---- phase 2 (per-wave): z = aT^g * z0 + sum_h aT^(g-1-h) * E_h ----
    {
        const float* Xp = x0 + d * NS + n0;
        const float* Bp = B + d * NS + n0;
#pragma unroll
        for (int k = 0; k < 16; ++k) {
            float x0v = Xp[k];
            if (x0v == 0.0f) { z[k] = 0.0f; }   // common/bench case
            else {
                float bt = (1.0f - a[k]) * Bp[k] / Ap[k];
                z[k] = (bt != 0.0f) ? (x0v / bt) : 0.0f;
            }
        }
    }
    if (g > 0) {
        float aT[16];
        float dTc = dt * (float)Tc;
#pragma unroll
        for (int k = 0; k < 16; ++k)
            aT[k] = expf(Ap[k] * dTc);          // a^Tc
        const float* Eb = S + ((size_t)b * DM + d) * NS + n0;
        for (int h = 0; h < g; ++h) {
            const float4* E4 = (const float4*)(Eb + (size_t)h * estride);
            float e[16];
#pragma unroll
            for (int j = 0; j < 4; ++j) {
                float4 v = E4[j];
                e[4*j] = v.x; e[4*j+1] = v.y; e[4*j+2] = v.z; e[4*j+3] = v.w;
            }
#pragma unroll
            for (int k = 0; k < 16; ++k)
                z[k] = fmaf(aT[k], z[k], e[k]);
        }
    }

    // ---- phase 3: full scan from true incoming state, emit y ----
    float cbt[16];
    {
        const float* Bp = B + d * NS + n0;
        const float* Cp = Cm + d * NS + n0;
#pragma unroll
        for (int k = 0; k < 16; ++k)
            cbt[k] = Cp[k] * ((1.0f - a[k]) * Bp[k] / Ap[k]);  // C * B_tilde
    }
    const float* gsrc = u + (size_t)b * SEQ * DM + (size_t)(g * Tc) * DM
                        + (size_t)(lane >> 2) * DM + d0 + ((lane & 3) << 2);
    float* yptr = y + (size_t)b * SEQ * DM + (size_t)(g * Tc) * DM + d;

    float4 rnext = *(const float4*)gsrc;
    *(float4*)slot0 = rnext;
    gsrc += tadv;
    rnext = *(const float4*)gsrc;
    gsrc += tadv;

    for (int tile = 0; tile < ntiles; ++tile) {
        int cur = tile & 1;
        if (tile + 1 < ntiles)
            *(float4*)(slot0 + (((tile + 1) & 1) << 8)) = rnext;
        if (tile + 2 < ntiles) {
            rnext = *(const float4*)gsrc;
            gsrc += tadv;
        }
        const float* tb = &tiles[wid][cur][0][0] + c;
#pragma unroll
        for (int s = 0; s < TSTEP; ++s) {
            float uv = tb[s << 4];              // broadcast ds_read_b32
            float p0 = 0.0f, p1 = 0.0f;
#pragma unroll
            for (int k = 0; k < 16; k += 2) {
                z[k]   = fmaf(a[k],   z[k],   uv); p0 = fmaf(cbt[k],   z[k],   p0);
                z[k+1] = fmaf(a[k+1], z[k+1], uv); p1 = fmaf(cbt[k+1], z[k+1], p1);
            }
            float p = p0 + p1;
            p += __shfl_xor(p, 1);   // combine the four quarter-state partials
            p += __shfl_xor(p, 2);
            if (sub == 0) yptr[s * DM] = p;  // imm-offset store, no ptr chain
        }
        yptr += tadv;
    }
}

// ---------------- fallback: proven r7 three-kernel path ----------------
__global__ __launch_bounds__(256, 2)
void pass1_kernel(const float* __restrict__ u,
                  const float* __restrict__ log_dt,
                  const float* __restrict__ A_real,
                  float* __restrict__ S, int Tc) {
    __shared__ float tiles[4][2][TSTEP][16];
    int wid  = threadIdx.x >> 6;
    int lane = threadIdx.x & 63;
    int wave = (blockIdx.x * blockDim.x + threadIdx.x) >> 6;
    int w  = wave & 511;
    int g  = wave >> 9;
    int b  = w >> 4;
    int d0 = (w & 15) << 4;
    int c   = lane >> 2;
    int sub = lane & 3;
    int d   = d0 + c;
    int n0  = sub << 4;

    float a[16], z[16];
    {
        float dt = expf(log_dt[d]);
        const float* Ap = A_real + d * NS + n0;
#pragma unroll
        for (int k = 0; k < 16; ++k) {
            a[k] = expf(Ap[k] * dt);
            z[k] = 0.0f;
        }
    }
    const float* gsrc = u + (size_t)b * SEQ * DM + (size_t)(g * Tc) * DM
                        + (size_t)(lane >> 2) * DM + d0 + ((lane & 3) << 2);
    const size_t tadv = (size_t)TSTEP * DM;
    float* slot0 = &tiles[wid][0][0][0] + (lane << 2);
    const int ntiles = Tc / TSTEP;

    float4 rnext = *(const float4*)gsrc;
    *(float4*)slot0 = rnext;
    gsrc += tadv;
    rnext = *(const float4*)gsrc;
    gsrc += tadv;

    for (int tile = 0; tile < ntiles; ++tile) {
        int cur = tile & 1;
        if (tile + 1 < ntiles)
            *(float4*)(slot0 + (((tile + 1) & 1) << 8)) = rnext;
        if (tile + 2 < ntiles) {
            rnext = *(const float4*)gsrc;
            gsrc += tadv;
        }
        const float* tb = &tiles[wid][cur][0][0] + c;
#pragma unroll
        for (int s = 0; s < TSTEP; ++s) {
            float uv = tb[s << 4];
#pragma unroll
            for (int k = 0; k < 16; ++k)
                z[k] = fmaf(a[k], z[k], uv);
        }
    }
    float* Sp = S + (((size_t)g * BATCH + b) * DM + d) * NS + n0;
    float4* Sp4 = (float4*)Sp;
#pragma unroll
    for (int j = 0; j < 4; ++j)
        Sp4[j] = make_float4(z[4*j], z[4*j+1], z[4*j+2], z[4*j+3]);
}

__global__ void pass2_kernel(float* __restrict__ S,
                             const float* __restrict__ log_dt,
                             const float* __restrict__ A_real,
                             const float* __restrict__ B,
                             const float* __restrict__ x0,
                             int C, int Tc) {
    int idx = blockIdx.x * blockDim.x + threadIdx.x;
    if (idx >= BATCH * DM * NS) return;
    int dn = idx & (DM * NS - 1);
    int d = dn >> 6;
    float ar = A_real[dn];
    float dt = expf(log_dt[d]);
    float aT = expf(ar * dt * (float)Tc);
    float x0v = x0[dn];
    float prev;
    if (x0v == 0.0f) {
        prev = 0.0f;
    } else {
        float at = expf(ar * dt);
        float bt = (1.0f - at) * B[dn] / ar;
        prev = (bt != 0.0f) ? (x0v / bt) : 0.0f;
    }
    const size_t stride = (size_t)BATCH * DM * NS;
    if (C == 16) {
        float v[15];
#pragma unroll
        for (int g = 0; g < 15; ++g) v[g] = S[(size_t)g * stride + idx];
#pragma unroll
        for (int g = 0; g < 15; ++g) {
            S[(size_t)g * stride + idx] = prev;
            prev = fmaf(aT, prev, v[g]);
        }
        S[15 * stride + idx] = prev;
    } else {
        for (int g = 0; g < C - 1; ++g) {
            float* p = S + (size_t)g * stride + idx;
            float s = *p;
            *p = prev;
            prev = fmaf(aT, prev, s);
        }
        S[(size_t)(C - 1) * stride + idx] = prev;
    }
}

__global__ __launch_bounds__(256, 2)
void pass3_kernel(const float* __restrict__ u,
                  const float* __restrict__ log_dt,
                  const float* __restrict__ A_real,
                  const float* __restrict__ B,
                  const float* __restrict__ Cm,
                  const float* __restrict__ S,
                  const float* __restrict__ x0,
                  float* __restrict__ y, int Tc, int useS) {
    __shared__ float tiles[4][2][TSTEP][16];
    int wid  = threadIdx.x >> 6;
    int lane = threadIdx.x & 63;
    int wave = (blockIdx.x * blockDim.x + threadIdx.x) >> 6;
    int w  = wave & 511;
    int g  = wave >> 9;
    int b  = w >> 4;
    int d0 = (w & 15) << 4;
    int c   = lane >> 2;
    int sub = lane & 3;
    int d   = d0 + c;
    int n0  = sub << 4;

    float a[16], cbt[16], z[16];
    {
        float dt = expf(log_dt[d]);
        const float* Ap = A_real + d * NS + n0;
        const float* Bp = B + d * NS + n0;
        const float* Cp = Cm + d * NS + n0;
#pragma unroll
        for (int k = 0; k < 16; ++k) {
            float ar = Ap[k];
            float at = expf(ar * dt);
            a[k] = at;
            cbt[k] = Cp[k] * ((1.0f - at) * Bp[k] / ar);
        }
        if (useS) {
            const float4* Sp4 = (const float4*)(S +
                (((size_t)g * BATCH + b) * DM + d) * NS + n0);
#pragma unroll
            for (int j = 0; j < 4; ++j) {
                float4 v = Sp4[j];
                z[4*j] = v.x; z[4*j+1] = v.y; z[4*j+2] = v.z; z[4*j+3] = v.w;
            }
        } else {
            const float* Xp = x0 + d * NS + n0;
#pragma unroll
            for (int k = 0; k < 16; ++k) {
                float x0v = Xp[k];
                if (x0v == 0.0f) { z[k] = 0.0f; }
                else {
                    float bt = (1.0f - a[k]) * Bp[k] / Ap[k];
                    z[k] = (bt != 0.0f) ? (x0v / bt) : 0.0f;
                }
            }
        }
    }

    const float* gsrc = u + (size_t)b * SEQ * DM + (size_t)(g * Tc) * DM
                        + (size_t)(lane >> 2) * DM + d0 + ((lane & 3) << 2);
    const size_t tadv = (size_t)TSTEP * DM;
    float* slot0 = &tiles[wid][0][0][0] + (lane << 2);
    const int ntiles = Tc / TSTEP;
    float* yptr = y + (size_t)b * SEQ * DM + (size_t)(g * Tc) * DM + d;

    float4 rnext = *(const float4*)gsrc;
    *(float4*)slot0 = rnext;
    gsrc += tadv;
    rnext = *(const float4*)gsrc;
    gsrc += tadv;

    for (int tile = 0; tile < ntiles; ++tile) {
        int cur = tile & 1;
        if (tile + 1 < ntiles)
            *(float4*)(slot0 + (((tile + 1) & 1) << 8)) = rnext;
        if (tile + 2 < ntiles) {
            rnext = *(const float4*)gsrc;
            gsrc += tadv;
        }
        const float* tb = &tiles[wid][cur][0][0] + c;
#pragma unroll
        for (int s = 0; s < TSTEP; ++s) {
            float uv = tb[s << 4];
            float p0 = 0.0f, p1 = 0.0f;
#pragma unroll
            for (int k = 0; k < 16; k += 2) {
                z[k]   = fmaf(a[k],   z[k],   uv); p0 = fmaf(cbt[k],   z[k],   p0);
                z[k+1] = fmaf(a[k+1], z[k+1], uv); p1 = fmaf(cbt[k+1], z[k+1], p1);
            }
            float p = p0 + p1;
            p += __shfl_xor(p, 1);
            p += __shfl_xor(p, 2);
            if (sub == 0) *yptr = p;
            yptr += DM;
        }
    }
}

extern "C" void kernel_launch(void* const* d_in, const int* in_sizes, int n_in,
                              void* d_out, int out_size, void* d_ws, size_t ws_size,
                              hipStream_t stream) {
    const float* u      = (const float*)d_in[0];
    const float* log_dt = (const float*)d_in[1];
    const float* A_real = (const float*)d_in[2];
    const float* B      = (const float*)d_in[3];
    const float* Cm     = (const float*)d_in[4];
    const float* x0     = (const float*)d_in[5];
    float* y = (float*)d_out;
    float* S = (float*)d_ws;

    const size_t per_chunk = (size_t)BATCH * DM * NS * sizeof(float);  // 2 MB
    int C = 16;
    while (C > 1 && (size_t)C * per_chunk > ws_size) C >>= 1;
    if ((size_t)C * per_chunk > ws_size) C = 1;
    int Tc = SEQ / C;

    // one-time check: can the fused kernel run cooperatively, all-resident?
    static int coop_state = -1;  // -1 unknown, 1 ok, 0 fallback
    if (coop_state == -1) {
        int ok = 0;
        int dev = 0, nb = 0;
        hipDeviceProp_t prop;
        if (hipGetDevice(&dev) == hipSuccess &&
            hipGetDeviceProperties(&prop, dev) == hipSuccess &&
            hipOccupancyMaxActiveBlocksPerMultiprocessor(
                &nb, (const void*)fused_kernel, 256, 0) == hipSuccess) {
            if (prop.cooperativeLaunch &&
                (long)nb * prop.multiProcessorCount >= (long)C * 128)
                ok = 1;
        }
        (void)hipGetLastError();
        coop_state = ok;
    }

    if (coop_state == 1) {
        int aTc = Tc, aC = C;
        void* args[] = {(void*)&u, (void*)&log_dt, (void*)&A_real, (void*)&B,
                        (void*)&Cm, (void*)&S, (void*)&x0, (void*)&y,
                        (void*)&aTc, (void*)&aC};
        hipError_t err = hipLaunchCooperativeKernel(
            (const void*)fused_kernel, dim3(C * 128), dim3(256), args, 0, stream);
        if (err == hipSuccess) return;
        (void)hipGetLastError();
        coop_state = 0;  // never retry; consistent fallback from now on
    }

    // fallback: proven r7 three-kernel path
    if (C > 1) {
        pass1_kernel<<<dim3((C - 1) * 128), dim3(256), 0, stream>>>(
            u, log_dt, A_real, S, Tc);
        pass2_kernel<<<dim3((BATCH * DM * NS) / 256), dim3(256), 0, stream>>>(
            S, log_dt, A_real, B, x0, C, Tc);
    }
    pass3_kernel<<<dim3(C * 128), dim3(256), 0, stream>>>(
        u, log_dt, A_real, B, Cm, S, x0, y, Tc, (C > 1) ? 1 : 0);
}